// Round 4
// baseline (331.478 us; speedup 1.0000x reference)
//
#include <hip/hip_runtime.h>

// Fused CircularBoundaryBlock:
//   out = relu(LN(x + W2 @ relu(W1 @ [roll(x,1), x, roll(x,-1)] + b1) + b2))
// B=4, N=65536, H=128, fp32 I/O, bf16 MFMA internally.
//
// R3 lessons: VGPR_Count=124 is arch-VGPRs only; unified VGPR+AGPR total
// (~128 weight regs + 64 acc) caps us at 2 waves/SIMD -> 8 waves/CU
// regardless of grid. So optimize the serial per-tile chain instead:
//  - prefetch next tile's x into regs (hides ~900cyc global latency behind GEMM1)
//  - column-interleave (cols 2l, 2l+1 per lane) -> packed b32 hs writes /
//    resid reads, f32x2 stores, gamma/beta/b1/b2 in 4 regs
//  - LN: vs written once (f32x2), stats by tid>>2 + 4-lane shuffle,
//    normalize from acc2 regs via s_mu/s_rs b128 reads
//  - 4 barriers/tile (was 6), no LDS aliasing (70KB/block, 2 blocks/CU)

typedef __bf16 bf16x8 __attribute__((ext_vector_type(8)));
typedef __bf16 bf16x4 __attribute__((ext_vector_type(4)));
typedef float  f32x4  __attribute__((ext_vector_type(4)));
typedef float  f32x2  __attribute__((ext_vector_type(2)));

#define H      128
#define NB     65536        // rows per batch
#define XS     136          // x LDS stride (bf16)
#define HSS    136          // h LDS stride (bf16)
#define VS     132          // v LDS stride (f32)
#define NTILES 4096
#define GRID   512

union PK { unsigned u; __bf16 b[2]; };

__device__ __forceinline__ void pf_load(const float* __restrict__ x, int tt, int tid,
                                        f32x4 pf[9]) {
    const int n0 = (tt & 1023) << 6;
    const size_t rowbase = (size_t)(tt >> 10) * NB;
#pragma unroll
    for (int i = 0; i < 8; ++i) {
        const int q = tid + 256 * i;
        const int r = q >> 5, c = q & 31;
        const int grow = (n0 - 1 + r + NB) & (NB - 1);
        pf[i] = *(const f32x4*)(x + ((rowbase + grow) * H + c * 4));
    }
    if (tid < 64) {
        const int q = 2048 + tid;
        const int r = q >> 5, c = q & 31;
        const int grow = (n0 - 1 + r + NB) & (NB - 1);
        pf[8] = *(const f32x4*)(x + ((rowbase + grow) * H + c * 4));
    }
}

__global__ __launch_bounds__(256, 2)
void cbb_kernel(const float* __restrict__ x, const float* __restrict__ W1,
                const float* __restrict__ b1, const float* __restrict__ W2,
                const float* __restrict__ b2, const float* __restrict__ gamma,
                const float* __restrict__ beta, float* __restrict__ out) {
    __shared__ __align__(16) __bf16 xs[66 * XS];   // 17952 B
    __shared__ __align__(16) __bf16 hs[64 * HSS];  // 17408 B
    __shared__ __align__(16) float  vs[64 * VS];   // 33792 B
    __shared__ __align__(16) float  s_mu[64], s_rs[64];

    const int tid  = threadIdx.x;
    const int wid  = tid >> 6;
    const int lane = tid & 63;
    const int l    = lane & 15;   // MFMA m / n index
    const int g    = lane >> 4;   // MFMA quad (k-chunk select)
    const int col0 = wid * 32;
    const int c0   = col0 + 2 * l;   // interleaved col for n-tile 0
    const int c1   = c0 + 1;         // interleaved col for n-tile 1

    const float b1r0 = b1[c0], b1r1 = b1[c1];
    const float b2r0 = b2[c0], b2r1 = b2[c1];
    const float gm0  = gamma[c0], gm1 = gamma[c1];
    const float bt0  = beta[c0],  bt1 = beta[c1];

    // ---- persistent weight B-fragments (bf16), interleaved col mapping ----
    bf16x8 w1f[12][2];
#pragma unroll
    for (int ks = 0; ks < 12; ++ks) {
#pragma unroll
        for (int ct = 0; ct < 2; ++ct) {
            const int cc = col0 + 2 * l + ct;
            bf16x8 f;
#pragma unroll
            for (int j = 0; j < 8; ++j)
                f[j] = (__bf16)W1[(ks * 32 + g * 8 + j) * H + cc];
            w1f[ks][ct] = f;
        }
    }
    bf16x8 w2f[4][2];
#pragma unroll
    for (int ks = 0; ks < 4; ++ks) {
#pragma unroll
        for (int ct = 0; ct < 2; ++ct) {
            const int cc = col0 + 2 * l + ct;
            bf16x8 f;
#pragma unroll
            for (int j = 0; j < 8; ++j)
                f[j] = (__bf16)W2[(ks * 32 + g * 8 + j) * H + cc];
            w2f[ks][ct] = f;
        }
    }

    f32x4 pf[9];
    pf_load(x, blockIdx.x, tid, pf);

    for (int t = blockIdx.x; t < NTILES; t += GRID) {
        const int n0 = (t & 1023) << 6;
        const size_t rowbase = (size_t)(t >> 10) * NB;

        // ---- stage prefetched x rows n0-1 .. n0+64 into LDS as bf16 ----
#pragma unroll
        for (int i = 0; i < 8; ++i) {
            const int q = tid + 256 * i;
            const int r = q >> 5, c = q & 31;
            bf16x4 v4;
            v4[0] = (__bf16)pf[i][0]; v4[1] = (__bf16)pf[i][1];
            v4[2] = (__bf16)pf[i][2]; v4[3] = (__bf16)pf[i][3];
            *(bf16x4*)(xs + r * XS + c * 4) = v4;
        }
        if (tid < 64) {
            const int q = 2048 + tid;
            const int r = q >> 5, c = q & 31;
            bf16x4 v4;
            v4[0] = (__bf16)pf[8][0]; v4[1] = (__bf16)pf[8][1];
            v4[2] = (__bf16)pf[8][2]; v4[3] = (__bf16)pf[8][3];
            *(bf16x4*)(xs + r * XS + c * 4) = v4;
        }
        __syncthreads();   // (B) xs ready

        // ---- prefetch next tile (latency hides behind GEMM1) ----
        const int tn = (t + GRID < NTILES) ? (t + GRID) : t;
        pf_load(x, tn, tid, pf);

        // ---- GEMM1: h = relu(cat @ W1 + b1) ----
        f32x4 acc[4][2];
#pragma unroll
        for (int rt = 0; rt < 4; ++rt)
#pragma unroll
            for (int ct = 0; ct < 2; ++ct)
                acc[rt][ct] = (f32x4){0.f, 0.f, 0.f, 0.f};

#pragma unroll
        for (int rt = 0; rt < 4; ++rt) {
            const int rb = rt * 16 + l;
#pragma unroll
            for (int ks = 0; ks < 12; ++ks) {
                const int k = ks * 32 + g * 8;          // k in [0,384)
                const bf16x8 a = *(const bf16x8*)(xs + (rb + (k >> 7)) * XS + (k & 127));
                acc[rt][0] = __builtin_amdgcn_mfma_f32_16x16x32_bf16(a, w1f[ks][0], acc[rt][0], 0, 0, 0);
                acc[rt][1] = __builtin_amdgcn_mfma_f32_16x16x32_bf16(a, w1f[ks][1], acc[rt][1], 0, 0, 0);
            }
        }

        // relu + bias -> hs, packed b32 (cols 2l, 2l+1 adjacent)
#pragma unroll
        for (int rt = 0; rt < 4; ++rt) {
#pragma unroll
            for (int i = 0; i < 4; ++i) {
                const int row = rt * 16 + g * 4 + i;
                PK p;
                p.b[0] = (__bf16)fmaxf(acc[rt][0][i] + b1r0, 0.f);
                p.b[1] = (__bf16)fmaxf(acc[rt][1][i] + b1r1, 0.f);
                *(unsigned*)(hs + row * HSS + c0) = p.u;
            }
        }
        __syncthreads();   // (C) hs ready

        // ---- GEMM2: delta = h @ W2 ----
        f32x4 acc2[4][2];
#pragma unroll
        for (int rt = 0; rt < 4; ++rt)
#pragma unroll
            for (int ct = 0; ct < 2; ++ct)
                acc2[rt][ct] = (f32x4){0.f, 0.f, 0.f, 0.f};

#pragma unroll
        for (int rt = 0; rt < 4; ++rt) {
            const int rb = rt * 16 + l;
#pragma unroll
            for (int ks = 0; ks < 4; ++ks) {
                const bf16x8 a = *(const bf16x8*)(hs + rb * HSS + ks * 32 + g * 8);
                acc2[rt][0] = __builtin_amdgcn_mfma_f32_16x16x32_bf16(a, w2f[ks][0], acc2[rt][0], 0, 0, 0);
                acc2[rt][1] = __builtin_amdgcn_mfma_f32_16x16x32_bf16(a, w2f[ks][1], acc2[rt][1], 0, 0, 0);
            }
        }

        // ---- residual (packed b32 xs read) + vs write (f32x2), keep in acc2 ----
#pragma unroll
        for (int rt = 0; rt < 4; ++rt) {
#pragma unroll
            for (int i = 0; i < 4; ++i) {
                const int row = rt * 16 + g * 4 + i;
                PK p;
                p.u = *(const unsigned*)(xs + (row + 1) * XS + c0);
                const float v0 = acc2[rt][0][i] + b2r0 + (float)p.b[0];
                const float v1 = acc2[rt][1][i] + b2r1 + (float)p.b[1];
                acc2[rt][0][i] = v0;
                acc2[rt][1][i] = v1;
                *(f32x2*)(vs + row * VS + c0) = (f32x2){v0, v1};
            }
        }
        __syncthreads();   // (D) vs ready

        // ---- LN stats: row = tid>>2, 32 cols/thread, 4-lane shuffle reduce ----
        {
            const int row = tid >> 2;
            const int cb  = (tid & 3) * 32;
            float s = 0.f, q = 0.f;
#pragma unroll
            for (int c8 = 0; c8 < 8; ++c8) {
                const f32x4 vv = *(const f32x4*)(vs + row * VS + cb + c8 * 4);
#pragma unroll
                for (int e = 0; e < 4; ++e) { s += vv[e]; q += vv[e] * vv[e]; }
            }
            s += __shfl_xor(s, 1); s += __shfl_xor(s, 2);
            q += __shfl_xor(q, 1); q += __shfl_xor(q, 2);
            if ((tid & 3) == 0) {
                const float muv = s * (1.f / 128.f);
                s_mu[row] = muv;
                s_rs[row] = rsqrtf(q * (1.f / 128.f) - muv * muv + 1e-5f);
            }
        }
        __syncthreads();   // (E) mu/rs ready

        // ---- normalize + relu + store directly from acc2 (C-layout) ----
#pragma unroll
        for (int rt = 0; rt < 4; ++rt) {
            const int r0 = rt * 16 + g * 4;
            const f32x4 mu4 = *(const f32x4*)(s_mu + r0);
            const f32x4 rs4 = *(const f32x4*)(s_rs + r0);
#pragma unroll
            for (int i = 0; i < 4; ++i) {
                const float o0 = fmaxf((acc2[rt][0][i] - mu4[i]) * rs4[i] * gm0 + bt0, 0.f);
                const float o1 = fmaxf((acc2[rt][1][i] - mu4[i]) * rs4[i] * gm1 + bt1, 0.f);
                *(f32x2*)(out + (rowbase + n0 + r0 + i) * H + c0) = (f32x2){o0, o1};
            }
        }
        // no trailing barrier needed: next xs write is separated from this
        // iteration's last xs/hs/vs/s_mu readers by barriers D and E.
    }
}

extern "C" void kernel_launch(void* const* d_in, const int* in_sizes, int n_in,
                              void* d_out, int out_size, void* d_ws, size_t ws_size,
                              hipStream_t stream) {
    const float* x     = (const float*)d_in[0];
    const float* W1    = (const float*)d_in[1];
    const float* b1    = (const float*)d_in[2];
    const float* W2    = (const float*)d_in[3];
    const float* b2    = (const float*)d_in[4];
    const float* gamma = (const float*)d_in[5];
    const float* beta  = (const float*)d_in[6];
    float* out = (float*)d_out;

    // grid 512: 8 tiles/block amortizes the 128-VGPR weight preamble;
    // occupancy is register-limited at 2 blocks/CU either way (R3 lesson).
    cbb_kernel<<<GRID, 256, 0, stream>>>(x, W1, b1, W2, b2, gamma, beta, out);
}